// Round 16
// baseline (80.979 us; speedup 1.0000x reference)
//
#include <hip/hip_runtime.h>
#include <hip/hip_bf16.h>

typedef __attribute__((ext_vector_type(8))) short short8;
typedef __attribute__((ext_vector_type(4))) short short4v;
typedef __attribute__((ext_vector_type(4))) float f32x4;
typedef __attribute__((ext_vector_type(16))) float f32x16;
typedef __attribute__((ext_vector_type(4))) int i32x4;
typedef __attribute__((ext_vector_type(16))) int i32x16;
typedef __attribute__((ext_vector_type(2))) unsigned u32x2;

namespace {
constexpr int NSEQ = 2048;
constexpr int NHEAD = 16;
constexpr int NDIM = 128;
constexpr int BKV = 32;
constexpr int VTS = 40;              // vt row stride (shorts); odd*16B -> conflict-free b128 column reads
constexpr int ROWI = NHEAD * NDIM;   // 2048 ints per seq row
constexpr int MID = 34;              // 2-way balanced split point
constexpr int NROWSH = 2 * 1024 * NHEAD;            // heavy rows (q>=1024) = 32768
constexpr size_t NPARTH = (size_t)NROWSH * NDIM;    // elems per heavy partial
}

__device__ __forceinline__ short i2bf(int v) {               // exact for |v|<=255
    union { float f; unsigned u; } x; x.f = (float)v;
    return (short)(x.u >> 16);
}
__device__ __forceinline__ short f2bf(float f) {             // RNE
    union { float f; unsigned u; } x; x.f = f;
    unsigned u = (x.u + 0x7fffu + ((x.u >> 16) & 1u)) >> 16;
    return (short)u;
}
__device__ __forceinline__ float bf2f(short s) {
    union { unsigned u; float f; } x; x.u = ((unsigned)(unsigned short)s) << 16;
    return x.f;
}
__device__ __forceinline__ unsigned pack8(const int4 &a) {
    return (unsigned)(a.x & 255) | ((unsigned)(a.y & 255) << 8) |
           ((unsigned)(a.z & 255) << 16) | ((unsigned)a.w << 24);
}
__device__ __forceinline__ void plswap(unsigned &a, unsigned &b) {
#if __has_builtin(__builtin_amdgcn_permlane32_swap)
    u32x2 r = __builtin_amdgcn_permlane32_swap(a, b, false, false);
    a = r[0]; b = r[1];
#else
    asm volatile("v_permlane32_swap_b32 %0, %1" : "+v"(a), "+v"(b));
#endif
}

// MODE: 0 = exact 512-block; 1 = 2-way heavy split (round-10/12 structure)
// NOTE: launch_bounds arg2 MUST stay <=2: arg2=4 empirically caps VGPR at 64 -> catastrophic
// scratch spill (rounds 9/11/13: VGPR_Count 64, WRITE_SIZE 152-466 MB).
// NOTE: ISSUE(next) must come AFTER __syncthreads(): the compiler drains vmcnt(0) before
// s_barrier, so loads issued pre-barrier serialize the whole phase on HBM/L2 latency.
template<int MODE>
__global__ __launch_bounds__(256, 2)
void qattn_fwd(const int* __restrict__ qq, const int* __restrict__ kq,
               const int* __restrict__ vq, const float* __restrict__ qsc,
               const float* __restrict__ ksc, const float* __restrict__ vsc,
               float* __restrict__ out, unsigned short* __restrict__ po,
               float* __restrict__ ml)
{
    const int id = blockIdx.x;
    const int bh = id & 31;                        // same bh -> same XCD (32%8==0)
    const int b = bh >> 4, h = bh & 15;
    const int t = threadIdx.x;
    const int lane = t & 63;
    const int l31 = lane & 31;
    const int h5 = lane >> 5;
    const int w = t >> 6;                          // wave 0..3

    __shared__ __align__(16) unsigned k_lds[2][BKV * 32];  // 8 KB, packed i8 rows, XOR-swz
    __shared__ __align__(16) short vt_lds[2][NDIM * VTS];  // 20 KB, V^T [d][kv]

    const float sc2 = qsc[h] * ksc[h] * (0.08838834764831845f * 1.4426950408889634f); // /sqrt(D)*log2e
    const float vscale = vsc[h];

    const int* kB = kq + (size_t)b * NSEQ * ROWI + h * NDIM;
    const int* vB = vq + (size_t)b * NSEQ * ROWI + h * NDIM;

    // staging decomposition (256 threads)
    const int kr  = t >> 3;            // K: row 0..31
    const int db  = t & 7;             // K: 16-int group (-> 4 packed dwords)
    const int kvh = t & 7;             // V: kv rows kvh*4..+3
    const int dgv = t >> 3;            // V: d cols dgv*4..+3

    // outMode: 0 = exact -> out; 1 = heavy-layout partial (part 0/1)
    auto run_segment = [&](int q0, int tBeg, int tEnd, int outMode, int part) {
        __syncthreads();               // protect LDS reuse across segments
        // ---- Q fragments (B-operand of 32x32x32_i8): lane owns q col = q0+l31 ----
        i32x4 qf[4];
        {
            const int* qp = qq + (size_t)(b * NSEQ + q0 + l31) * ROWI + h * NDIM + h5 * 16;
            #pragma unroll
            for (int c = 0; c < 4; ++c) {
                int4 a0 = *(const int4*)(qp + c * 32);
                int4 a1 = *(const int4*)(qp + c * 32 + 4);
                int4 a2 = *(const int4*)(qp + c * 32 + 8);
                int4 a3 = *(const int4*)(qp + c * 32 + 12);
                i32x4 f = { (int)pack8(a0), (int)pack8(a1), (int)pack8(a2), (int)pack8(a3) };
                qf[c] = f;
            }
        }
        f32x16 o_acc[4];
        #pragma unroll
        for (int dt = 0; dt < 4; ++dt)
            #pragma unroll
            for (int r = 0; r < 16; ++r) o_acc[dt][r] = 0.f;
        float m_run = -1e30f, l_run = 0.f;
        const int q_hi = q0 + 31;

        int4 ka0, ka1, ka2, ka3, va0, va1, va2, va3;
        auto ISSUE = [&](int tt) {
            const int kv = tt * BKV;
            const int* kp = kB + (kv + kr) * ROWI + db * 16;
            ka0 = *(const int4*)kp;       ka1 = *(const int4*)(kp + 4);
            ka2 = *(const int4*)(kp + 8); ka3 = *(const int4*)(kp + 12);
            const int* vp = vB + (kv + kvh * 4) * ROWI + dgv * 4;
            va0 = *(const int4*)vp;
            va1 = *(const int4*)(vp + ROWI);
            va2 = *(const int4*)(vp + 2 * ROWI);
            va3 = *(const int4*)(vp + 3 * ROWI);
        };
        auto WRITE = [&](int buf) {
            i32x4 kk = { (int)pack8(ka0), (int)pack8(ka1), (int)pack8(ka2), (int)pack8(ka3) };
            *(i32x4*)&k_lds[buf][kr * 32 + ((db * 4) ^ ((kr & 7) << 2))] = kk;   // 16B-group XOR swz
            short4v c0 = { i2bf(va0.x), i2bf(va1.x), i2bf(va2.x), i2bf(va3.x) };
            short4v c1 = { i2bf(va0.y), i2bf(va1.y), i2bf(va2.y), i2bf(va3.y) };
            short4v c2 = { i2bf(va0.z), i2bf(va1.z), i2bf(va2.z), i2bf(va3.z) };
            short4v c3 = { i2bf(va0.w), i2bf(va1.w), i2bf(va2.w), i2bf(va3.w) };
            short* vb = &vt_lds[buf][(dgv * 4) * VTS + kvh * 4];
            *(short4v*)(vb + 0 * VTS) = c0;
            *(short4v*)(vb + 1 * VTS) = c1;
            *(short4v*)(vb + 2 * VTS) = c2;
            *(short4v*)(vb + 3 * VTS) = c3;
        };

        ISSUE(tBeg);
        for (int tt = tBeg; tt < tEnd; ++tt) {
            const int buf = (tt - tBeg) & 1;
            WRITE(buf);                    // vmcnt naturally drained: consumes ISSUE(tt) regs
            __syncthreads();               // free drain: no outstanding global loads here
            if (tt + 1 < tEnd) ISSUE(tt + 1);   // prefetch AFTER barrier -> overlaps compute

            const int kv0 = tt * BKV;
            if (kv0 > q_hi) continue;      // wave-uniform causal skip

            // ---- QK^T (swapped, int8 exact): C = S^T, col = l31 = q, kv = (r&3)+8*(r>>2)+4*h5 ----
            i32x16 s;
            #pragma unroll
            for (int r = 0; r < 16; ++r) s[r] = 0;
            __builtin_amdgcn_s_setprio(1);
            #pragma unroll
            for (int c = 0; c < 4; ++c) {
                const i32x4 kb = *(const i32x4*)&k_lds[buf][l31 * 32 + ((c * 8 + h5 * 4) ^ ((l31 & 7) << 2))];
                s = __builtin_amdgcn_mfma_i32_32x32x32_i8(kb, qf[c], s, 0, 0, 0);
            }
            __builtin_amdgcn_s_setprio(0);

            // ---- mask (diag tile only) + int->f32 (exact, |s| < 2^24) ----
            float sv[16];
            if (kv0 < q0) {
                #pragma unroll
                for (int r = 0; r < 16; ++r) sv[r] = (float)s[r];
            } else {                       // kv0 == q0 diag
                #pragma unroll
                for (int r = 0; r < 16; ++r) {
                    const int kvr = (r & 3) + 8 * (r >> 2) + 4 * h5;
                    sv[r] = (kvr <= l31) ? (float)s[r] : -1e30f;
                }
            }

            // ---- in-register softmax (raw-s domain; sc2 > 0 so max commutes) ----
            float rmax = sv[0];
            #pragma unroll
            for (int r = 1; r < 16; ++r) rmax = fmaxf(rmax, sv[r]);
            rmax = fmaxf(rmax, __shfl_xor(rmax, 32, 64));      // cross-half max
            const bool needr = (rmax - m_run) * sc2 > 8.0f;    // T13 defer-rescale
            if (__any((int)needr)) {
                const float mn = fmaxf(m_run, rmax);
                const float sf = exp2f((m_run - mn) * sc2);
                m_run = mn;
                l_run *= sf;
                #pragma unroll
                for (int dt = 0; dt < 4; ++dt)
                    #pragma unroll
                    for (int r = 0; r < 16; ++r) o_acc[dt][r] *= sf;
            }
            const float nm = m_run * sc2;
            float p[16];
            float ps = 0.f;
            #pragma unroll
            for (int r = 0; r < 16; ++r) {
                p[r] = exp2f(__builtin_fmaf(sv[r], sc2, -nm));
                ps += p[r];
            }
            ps += __shfl_xor(ps, 32, 64);                      // cross-half sum
            l_run += ps;

            // ---- P -> bf16 B-frags fully in-register (T12) ----
            unsigned pw0[4], pw1[4];
            {
                unsigned A0, A1, B0, B1;
                asm("v_cvt_pk_bf16_f32 %0, %1, %2" : "=v"(A0) : "v"(p[0]),  "v"(p[1]));
                asm("v_cvt_pk_bf16_f32 %0, %1, %2" : "=v"(A1) : "v"(p[2]),  "v"(p[3]));
                asm("v_cvt_pk_bf16_f32 %0, %1, %2" : "=v"(B0) : "v"(p[4]),  "v"(p[5]));
                asm("v_cvt_pk_bf16_f32 %0, %1, %2" : "=v"(B1) : "v"(p[6]),  "v"(p[7]));
                plswap(A0, B0);
                plswap(A1, B1);
                pw0[0] = A0; pw0[1] = A1; pw0[2] = B0; pw0[3] = B1;
                asm("v_cvt_pk_bf16_f32 %0, %1, %2" : "=v"(A0) : "v"(p[8]),  "v"(p[9]));
                asm("v_cvt_pk_bf16_f32 %0, %1, %2" : "=v"(A1) : "v"(p[10]), "v"(p[11]));
                asm("v_cvt_pk_bf16_f32 %0, %1, %2" : "=v"(B0) : "v"(p[12]), "v"(p[13]));
                asm("v_cvt_pk_bf16_f32 %0, %1, %2" : "=v"(B1) : "v"(p[14]), "v"(p[15]));
                plswap(A0, B0);
                plswap(A1, B1);
                pw1[0] = A0; pw1[1] = A1; pw1[2] = B0; pw1[3] = B1;
            }
            union { unsigned u4[4]; short8 v; } pf0, pf1;
            pf0.u4[0]=pw0[0]; pf0.u4[1]=pw0[1]; pf0.u4[2]=pw0[2]; pf0.u4[3]=pw0[3];
            pf1.u4[0]=pw1[0]; pf1.u4[1]=pw1[1]; pf1.u4[2]=pw1[2]; pf1.u4[3]=pw1[3];

            // ---- PV (swapped): O^T[d][q] += V^T[d][kv] * P^T[kv][q] ----
            __builtin_amdgcn_s_setprio(1);
            #pragma unroll
            for (int dt = 0; dt < 4; ++dt) {
                const int drow = dt * 32 + l31;
                const short8 vb0 = *(const short8*)&vt_lds[buf][drow * VTS + h5 * 8];
                o_acc[dt] = __builtin_amdgcn_mfma_f32_32x32x16_bf16(vb0, pf0.v, o_acc[dt], 0, 0, 0);
                const short8 vb1 = *(const short8*)&vt_lds[buf][drow * VTS + 16 + h5 * 8];
                o_acc[dt] = __builtin_amdgcn_mfma_f32_32x32x16_bf16(vb1, pf1.v, o_acc[dt], 0, 0, 0);
            }
            __builtin_amdgcn_s_setprio(0);
        }

        // ---- epilogue ----
        const int qrow = q0 + l31;
        if (outMode == 0) {
            const float sr = vscale / l_run;
            float* op = out + ((size_t)(b * NSEQ + qrow) * NHEAD + h) * NDIM;
            #pragma unroll
            for (int dt = 0; dt < 4; ++dt) {
                #pragma unroll
                for (int gq = 0; gq < 4; ++gq) {
                    f32x4 v = { o_acc[dt][gq * 4 + 0] * sr, o_acc[dt][gq * 4 + 1] * sr,
                                o_acc[dt][gq * 4 + 2] * sr, o_acc[dt][gq * 4 + 3] * sr };
                    *(f32x4*)(op + dt * 32 + 8 * gq + 4 * h5) = v;
                }
            }
        } else {
            const size_t hr = ((size_t)b * 1024 + (qrow - 1024)) * NHEAD + h;
            short* pp = (short*)(po + (size_t)part * NPARTH + hr * NDIM);
            #pragma unroll
            for (int dt = 0; dt < 4; ++dt) {
                #pragma unroll
                for (int gq = 0; gq < 4; ++gq) {
                    short4v v = { f2bf(o_acc[dt][gq * 4 + 0]), f2bf(o_acc[dt][gq * 4 + 1]),
                                  f2bf(o_acc[dt][gq * 4 + 2]), f2bf(o_acc[dt][gq * 4 + 3]) };
                    *(short4v*)(pp + dt * 32 + 8 * gq + 4 * h5) = v;
                }
            }
            if (h5 == 0) {
                float* mlp = ml + (size_t)part * (2 * NROWSH) + hr * 2;
                mlp[0] = m_run;
                mlp[1] = l_run;
            }
        }
    };

    if constexpr (MODE == 1) {
        const int u = id >> 5;                 // 0..15
        const int k = u & 7;                   // pair index
        const int role = u >> 3;               // 0 = A, 1 = B
        const int jqH = 15 - k, jqL = k;
        const int TH = (16 - k) * 4, TL = (k + 1) * 4;
        const int q0H = jqH * 128 + w * 32;
        if (role == 0) {
            run_segment(q0H, 0, MID, 1, 0);                          // heavy prefix (34)
        } else {
            run_segment(q0H, MID, TH, 1, 1);                         // heavy suffix
            run_segment(jqL * 128 + w * 32, 0, TL, 0, 0);            // light exact; total 34
        }
    } else {
        const int idx = id >> 5;
        const int jq = (idx < 8) ? (15 - idx) : (idx - 8);
        run_segment(jq * 128 + w * 32, 0, (jq + 1) * 4, 0, 0);       // exact path
    }
}

// merge heavy-row 2-way partials
__global__ __launch_bounds__(256)
void qattn_combine2(const unsigned short* __restrict__ po, const float* __restrict__ ml,
                    const float* __restrict__ qsc, const float* __restrict__ ksc,
                    const float* __restrict__ vsc, float* __restrict__ out)
{
    const int gid = blockIdx.x * 256 + threadIdx.x;   // NROWSH*16 threads
    const int hr = gid >> 4;
    const int d0 = (gid & 15) * 8;
    const int h = hr & 15;
    const int q = 1024 + ((hr >> 4) & 1023);
    const int b = hr >> 14;
    const float sc2 = qsc[h] * ksc[h] * (0.08838834764831845f * 1.4426950408889634f);
    const float m0 = ml[(size_t)hr * 2 + 0], l0 = ml[(size_t)hr * 2 + 1];
    const float m1 = ml[(size_t)2 * NROWSH + hr * 2 + 0], l1 = ml[(size_t)2 * NROWSH + hr * 2 + 1];
    const float M = fmaxf(m0, m1);
    const float w0 = exp2f((m0 - M) * sc2);
    const float w1 = exp2f((m1 - M) * sc2);
    const float sr = vsc[h] / __builtin_fmaf(w0, l0, w1 * l1);
    const float a0 = w0 * sr, a1 = w1 * sr;
    const short* x = (const short*)po + (size_t)hr * NDIM + d0;
    const short* y = (const short*)(po + NPARTH) + (size_t)hr * NDIM + d0;
    short4v x0 = *(const short4v*)x;
    short4v x1 = *(const short4v*)(x + 4);
    short4v y0 = *(const short4v*)y;
    short4v y1 = *(const short4v*)(y + 4);
    f32x4 o0, o1;
    #pragma unroll
    for (int i = 0; i < 4; ++i) {
        o0[i] = __builtin_fmaf(a0, bf2f(x0[i]), a1 * bf2f(y0[i]));
        o1[i] = __builtin_fmaf(a0, bf2f(x1[i]), a1 * bf2f(y1[i]));
    }
    float* op = out + ((size_t)(b * NSEQ + q) * NHEAD + h) * NDIM + d0;
    *(f32x4*)op = o0;
    *(f32x4*)(op + 4) = o1;
}

extern "C" void kernel_launch(void* const* d_in, const int* in_sizes, int n_in,
                              void* d_out, int out_size, void* d_ws, size_t ws_size,
                              hipStream_t stream) {
    const int* qq = (const int*)d_in[0];
    const int* kq = (const int*)d_in[1];
    const int* vq = (const int*)d_in[2];
    const float* qsc = (const float*)d_in[3];
    const float* ksc = (const float*)d_in[4];
    const float* vsc = (const float*)d_in[5];
    float* out = (float*)d_out;
    (void)in_sizes; (void)n_in; (void)out_size;

    const size_t need2 = NPARTH * 2 * sizeof(unsigned short)      // two bf16 partial halves
                       + (size_t)NROWSH * 4 * sizeof(float);      // two (m,l) arrays
    if (ws_size >= need2) {
        unsigned short* po = (unsigned short*)d_ws;
        float* ml = (float*)((char*)d_ws + NPARTH * 2 * sizeof(unsigned short));
        qattn_fwd<1><<<dim3(512), dim3(256), 0, stream>>>(qq, kq, vq, qsc, ksc, vsc, out, po, ml);
        qattn_combine2<<<dim3(NROWSH * 16 / 256), dim3(256), 0, stream>>>(po, ml, qsc, ksc, vsc, out);
    } else {
        qattn_fwd<0><<<dim3(512), dim3(256), 0, stream>>>(qq, kq, vq, qsc, ksc, vsc, out, nullptr, nullptr);
    }
}

// Round 17
// 78.532 us; speedup vs baseline: 1.0312x; 1.0312x over previous
//
#include <hip/hip_runtime.h>
#include <hip/hip_bf16.h>

typedef __attribute__((ext_vector_type(8))) short short8;
typedef __attribute__((ext_vector_type(4))) short short4v;
typedef __attribute__((ext_vector_type(4))) float f32x4;
typedef __attribute__((ext_vector_type(16))) float f32x16;
typedef __attribute__((ext_vector_type(4))) int i32x4;
typedef __attribute__((ext_vector_type(16))) int i32x16;
typedef __attribute__((ext_vector_type(2))) unsigned u32x2;

namespace {
constexpr int NSEQ = 2048;
constexpr int NHEAD = 16;
constexpr int NDIM = 128;
constexpr int VTP = 72;              // V^T row stride (shorts); 144B = 9*16B -> conflict-free b128 column reads
constexpr int ROWI = NHEAD * NDIM;   // 2048 ints per seq row
constexpr int MIDP = 18;             // balanced 64-kv phase split: every block runs exactly 18 phases
constexpr int NROWSH = 2 * 1024 * NHEAD;            // heavy rows (q>=1024) = 32768
constexpr size_t NPARTH = (size_t)NROWSH * NDIM;    // elems per heavy partial
}

__device__ __forceinline__ short i2bf(int v) {               // exact for |v|<=255
    union { float f; unsigned u; } x; x.f = (float)v;
    return (short)(x.u >> 16);
}
__device__ __forceinline__ short f2bf(float f) {             // RNE
    union { float f; unsigned u; } x; x.f = f;
    unsigned u = (x.u + 0x7fffu + ((x.u >> 16) & 1u)) >> 16;
    return (short)u;
}
__device__ __forceinline__ float bf2f(short s) {
    union { unsigned u; float f; } x; x.u = ((unsigned)(unsigned short)s) << 16;
    return x.f;
}
__device__ __forceinline__ unsigned pack8(const int4 &a) {
    return (unsigned)(a.x & 255) | ((unsigned)(a.y & 255) << 8) |
           ((unsigned)(a.z & 255) << 16) | ((unsigned)a.w << 24);
}
__device__ __forceinline__ void plswap(unsigned &a, unsigned &b) {
#if __has_builtin(__builtin_amdgcn_permlane32_swap)
    u32x2 r = __builtin_amdgcn_permlane32_swap(a, b, false, false);
    a = r[0]; b = r[1];
#else
    asm volatile("v_permlane32_swap_b32 %0, %1" : "+v"(a), "+v"(b));
#endif
}

// MODE: 0 = no-ws exact fallback; 1 = heavy/light supertile pairs + balanced role split
// NOTE: launch_bounds arg2 MUST stay <=2: higher values cap VGPR at 64 -> catastrophic
// scratch spill (rounds 9/11/13: VGPR_Count 64, WRITE_SIZE 152-466 MB).
template<int MODE>
__global__ __launch_bounds__(512, 2)
void qattn_fwd(const int* __restrict__ qq, const int* __restrict__ kq,
               const int* __restrict__ vq, const float* __restrict__ qsc,
               const float* __restrict__ ksc, const float* __restrict__ vsc,
               float* __restrict__ out, unsigned short* __restrict__ po,
               float* __restrict__ ml)
{
    const int id = blockIdx.x;
    const int bh = id & 31;                        // same bh -> same XCD (32%8==0)
    const int b = bh >> 4, h = bh & 15;
    const int t = threadIdx.x;
    const int lane = t & 63;
    const int l31 = lane & 31;
    const int h5 = lane >> 5;
    const int w = t >> 6;                          // wave 0..7; q0 = qbase + w*32

    __shared__ __align__(16) unsigned k_lds[2][2][32 * 32]; // 16 KB: [dbuf][half][row*32+dw] packed i8, swz
    __shared__ __align__(16) short vt_lds[2][NDIM * VTP];   // 36.9 KB: [dbuf] V^T [d][kv 0..63]

    const float sc2 = qsc[h] * ksc[h] * (0.08838834764831845f * 1.4426950408889634f); // /sqrt(D)*log2e
    const float vscale = vsc[h];

    const int* kB = kq + (size_t)b * NSEQ * ROWI + h * NDIM;
    const int* vB = vq + (size_t)b * NSEQ * ROWI + h * NDIM;

    // staging decomposition (512 threads, 64 kv rows per phase)
    const int kr  = t >> 3;            // K: row 0..63
    const int db  = t & 7;             // K: 16-int group
    const int kvh = t & 15;            // V: kv rows kvh*4..+3
    const int dgv = t >> 4;            // V: d cols dgv*4..+3

    // outMode: 0 = exact -> out; 1 = heavy-layout bf16 partial `part`
    auto run_segment = [&](int qbase, int tBeg, int tEnd, int outMode, int part) {
        __syncthreads();               // previous segment's LDS fully consumed
        const int q0 = qbase + w * 32;
        const int q_hi = q0 + 31;

        // ---- Q fragments (B-operand of 32x32x32_i8) ----
        i32x4 qf[4];
        {
            const int* qp = qq + (size_t)(b * NSEQ + q0 + l31) * ROWI + h * NDIM + h5 * 16;
            #pragma unroll
            for (int c = 0; c < 4; ++c) {
                int4 a0 = *(const int4*)(qp + c * 32);
                int4 a1 = *(const int4*)(qp + c * 32 + 4);
                int4 a2 = *(const int4*)(qp + c * 32 + 8);
                int4 a3 = *(const int4*)(qp + c * 32 + 12);
                i32x4 f = { (int)pack8(a0), (int)pack8(a1), (int)pack8(a2), (int)pack8(a3) };
                qf[c] = f;
            }
        }
        f32x16 o_acc[4];
        #pragma unroll
        for (int dt = 0; dt < 4; ++dt)
            #pragma unroll
            for (int r = 0; r < 16; ++r) o_acc[dt][r] = 0.f;
        float m_run = -1e30f, l_run = 0.f;

        int4 ka0, ka1, ka2, ka3, va0, va1, va2, va3;
        auto ISSUE = [&](int u) {
            const int kv = u * 64;
            const int* kp = kB + (kv + kr) * ROWI + db * 16;
            ka0 = *(const int4*)kp;       ka1 = *(const int4*)(kp + 4);
            ka2 = *(const int4*)(kp + 8); ka3 = *(const int4*)(kp + 12);
            const int* vp = vB + (kv + kvh * 4) * ROWI + dgv * 4;
            va0 = *(const int4*)vp;
            va1 = *(const int4*)(vp + ROWI);
            va2 = *(const int4*)(vp + 2 * ROWI);
            va3 = *(const int4*)(vp + 3 * ROWI);
        };
        auto WRITE = [&](int buf) {
            const int kt = kr >> 5, ri = kr & 31;
            i32x4 kk = { (int)pack8(ka0), (int)pack8(ka1), (int)pack8(ka2), (int)pack8(ka3) };
            *(i32x4*)&k_lds[buf][kt][ri * 32 + ((db * 4) ^ ((ri & 7) << 2))] = kk;
            short4v c0 = { i2bf(va0.x), i2bf(va1.x), i2bf(va2.x), i2bf(va3.x) };
            short4v c1 = { i2bf(va0.y), i2bf(va1.y), i2bf(va2.y), i2bf(va3.y) };
            short4v c2 = { i2bf(va0.z), i2bf(va1.z), i2bf(va2.z), i2bf(va3.z) };
            short4v c3 = { i2bf(va0.w), i2bf(va1.w), i2bf(va2.w), i2bf(va3.w) };
            short* vb = &vt_lds[buf][(dgv * 4) * VTP + kvh * 4];
            *(short4v*)(vb + 0 * VTP) = c0;
            *(short4v*)(vb + 1 * VTP) = c1;
            *(short4v*)(vb + 2 * VTP) = c2;
            *(short4v*)(vb + 3 * VTP) = c3;
        };

        // prologue: depth-2 pipeline fill
        ISSUE(tBeg);
        WRITE(0);                          // buf0 <- tile tBeg
        if (tBeg + 1 < tEnd) ISSUE(tBeg + 1);
        __syncthreads();

        for (int u = tBeg; u < tEnd; ++u) {
            const int buf = (u - tBeg) & 1;
            if (u + 1 < tEnd) {
                WRITE(buf ^ 1);            // consumes ISSUE(u+1) regs (issued a full phase ago)
                if (u + 2 < tEnd) ISSUE(u + 2);
            }

            const int kv0 = u * 64;
            if (kv0 <= q_hi) {             // wave-uniform causal participation
                const bool doB = (kv0 + 32 <= q_hi);
                const int swd = (l31 & 7) << 2;

                // ---- QK^T (swapped, int8 exact): col = l31 = q, kv = (r&3)+8*(r>>2)+4*h5 ----
                i32x16 sA, sB;
                #pragma unroll
                for (int r = 0; r < 16; ++r) { sA[r] = 0; sB[r] = 0; }
                __builtin_amdgcn_s_setprio(1);
                #pragma unroll
                for (int c = 0; c < 4; ++c) {
                    const i32x4 kbA = *(const i32x4*)&k_lds[buf][0][l31 * 32 + ((c * 8 + h5 * 4) ^ swd)];
                    sA = __builtin_amdgcn_mfma_i32_32x32x32_i8(kbA, qf[c], sA, 0, 0, 0);
                }
                if (doB) {
                    #pragma unroll
                    for (int c = 0; c < 4; ++c) {
                        const i32x4 kbB = *(const i32x4*)&k_lds[buf][1][l31 * 32 + ((c * 8 + h5 * 4) ^ swd)];
                        sB = __builtin_amdgcn_mfma_i32_32x32x32_i8(kbB, qf[c], sB, 0, 0, 0);
                    }
                }
                __builtin_amdgcn_s_setprio(0);

                // ---- mask + exact int->f32 ----
                float svA[16], svB[16];
                if (kv0 < q0) {
                    #pragma unroll
                    for (int r = 0; r < 16; ++r) svA[r] = (float)sA[r];
                } else {                   // kv0 == q0 diagonal
                    #pragma unroll
                    for (int r = 0; r < 16; ++r) {
                        const int kvr = (r & 3) + 8 * (r >> 2) + 4 * h5;
                        svA[r] = (kvr <= l31) ? (float)sA[r] : -1e30f;
                    }
                }
                if (doB) {
                    if (kv0 + 32 < q0) {
                        #pragma unroll
                        for (int r = 0; r < 16; ++r) svB[r] = (float)sB[r];
                    } else {               // kv0+32 == q0 diagonal
                        #pragma unroll
                        for (int r = 0; r < 16; ++r) {
                            const int kvr = (r & 3) + 8 * (r >> 2) + 4 * h5;
                            svB[r] = (kvr <= l31) ? (float)sB[r] : -1e30f;
                        }
                    }
                }

                // ---- merged online softmax over up to 64 kv ----
                float rmax = svA[0];
                #pragma unroll
                for (int r = 1; r < 16; ++r) rmax = fmaxf(rmax, svA[r]);
                if (doB) {
                    #pragma unroll
                    for (int r = 0; r < 16; ++r) rmax = fmaxf(rmax, svB[r]);
                }
                rmax = fmaxf(rmax, __shfl_xor(rmax, 32, 64));
                const bool needr = (rmax - m_run) * sc2 > 8.0f;    // T13 defer-rescale
                if (__any((int)needr)) {
                    const float mn = fmaxf(m_run, rmax);
                    const float sf = exp2f((m_run - mn) * sc2);
                    m_run = mn;
                    l_run *= sf;
                    #pragma unroll
                    for (int dt = 0; dt < 4; ++dt)
                        #pragma unroll
                        for (int r = 0; r < 16; ++r) o_acc[dt][r] *= sf;
                }
                const float nm = m_run * sc2;
                float ps = 0.f;
                float pA[16], pB[16];
                #pragma unroll
                for (int r = 0; r < 16; ++r) {
                    pA[r] = exp2f(__builtin_fmaf(svA[r], sc2, -nm));
                    ps += pA[r];
                }
                if (doB) {
                    #pragma unroll
                    for (int r = 0; r < 16; ++r) {
                        pB[r] = exp2f(__builtin_fmaf(svB[r], sc2, -nm));
                        ps += pB[r];
                    }
                }
                ps += __shfl_xor(ps, 32, 64);
                l_run += ps;

                // ---- P -> bf16 B-frags in-register (T12) ----
                union { unsigned u4[4]; short8 v; } pfA0, pfA1, pfB0, pfB1;
                {
                    unsigned A0, A1, B0, B1;
                    asm("v_cvt_pk_bf16_f32 %0, %1, %2" : "=v"(A0) : "v"(pA[0]),  "v"(pA[1]));
                    asm("v_cvt_pk_bf16_f32 %0, %1, %2" : "=v"(A1) : "v"(pA[2]),  "v"(pA[3]));
                    asm("v_cvt_pk_bf16_f32 %0, %1, %2" : "=v"(B0) : "v"(pA[4]),  "v"(pA[5]));
                    asm("v_cvt_pk_bf16_f32 %0, %1, %2" : "=v"(B1) : "v"(pA[6]),  "v"(pA[7]));
                    plswap(A0, B0); plswap(A1, B1);
                    pfA0.u4[0] = A0; pfA0.u4[1] = A1; pfA0.u4[2] = B0; pfA0.u4[3] = B1;
                    asm("v_cvt_pk_bf16_f32 %0, %1, %2" : "=v"(A0) : "v"(pA[8]),  "v"(pA[9]));
                    asm("v_cvt_pk_bf16_f32 %0, %1, %2" : "=v"(A1) : "v"(pA[10]), "v"(pA[11]));
                    asm("v_cvt_pk_bf16_f32 %0, %1, %2" : "=v"(B0) : "v"(pA[12]), "v"(pA[13]));
                    asm("v_cvt_pk_bf16_f32 %0, %1, %2" : "=v"(B1) : "v"(pA[14]), "v"(pA[15]));
                    plswap(A0, B0); plswap(A1, B1);
                    pfA1.u4[0] = A0; pfA1.u4[1] = A1; pfA1.u4[2] = B0; pfA1.u4[3] = B1;
                    if (doB) {
                        asm("v_cvt_pk_bf16_f32 %0, %1, %2" : "=v"(A0) : "v"(pB[0]),  "v"(pB[1]));
                        asm("v_cvt_pk_bf16_f32 %0, %1, %2" : "=v"(A1) : "v"(pB[2]),  "v"(pB[3]));
                        asm("v_cvt_pk_bf16_f32 %0, %1, %2" : "=v"(B0) : "v"(pB[4]),  "v"(pB[5]));
                        asm("v_cvt_pk_bf16_f32 %0, %1, %2" : "=v"(B1) : "v"(pB[6]),  "v"(pB[7]));
                        plswap(A0, B0); plswap(A1, B1);
                        pfB0.u4[0] = A0; pfB0.u4[1] = A1; pfB0.u4[2] = B0; pfB0.u4[3] = B1;
                        asm("v_cvt_pk_bf16_f32 %0, %1, %2" : "=v"(A0) : "v"(pB[8]),  "v"(pB[9]));
                        asm("v_cvt_pk_bf16_f32 %0, %1, %2" : "=v"(A1) : "v"(pB[10]), "v"(pB[11]));
                        asm("v_cvt_pk_bf16_f32 %0, %1, %2" : "=v"(B0) : "v"(pB[12]), "v"(pB[13]));
                        asm("v_cvt_pk_bf16_f32 %0, %1, %2" : "=v"(B1) : "v"(pB[14]), "v"(pB[15]));
                        plswap(A0, B0); plswap(A1, B1);
                        pfB1.u4[0] = A0; pfB1.u4[1] = A1; pfB1.u4[2] = B0; pfB1.u4[3] = B1;
                    }
                }

                // ---- PV (swapped): O^T[d][q] += V^T[d][kv] * P^T[kv][q] ----
                __builtin_amdgcn_s_setprio(1);
                #pragma unroll
                for (int dt = 0; dt < 4; ++dt) {
                    const int drow = dt * 32 + l31;
                    const short8 vbA0 = *(const short8*)&vt_lds[buf][drow * VTP + h5 * 8];
                    o_acc[dt] = __builtin_amdgcn_mfma_f32_32x32x16_bf16(vbA0, pfA0.v, o_acc[dt], 0, 0, 0);
                    const short8 vbA1 = *(const short8*)&vt_lds[buf][drow * VTP + 16 + h5 * 8];
                    o_acc[dt] = __builtin_amdgcn_mfma_f32_32x32x16_bf16(vbA1, pfA1.v, o_acc[dt], 0, 0, 0);
                    if (doB) {
                        const short8 vbB0 = *(const short8*)&vt_lds[buf][drow * VTP + 32 + h5 * 8];
                        o_acc[dt] = __builtin_amdgcn_mfma_f32_32x32x16_bf16(vbB0, pfB0.v, o_acc[dt], 0, 0, 0);
                        const short8 vbB1 = *(const short8*)&vt_lds[buf][drow * VTP + 48 + h5 * 8];
                        o_acc[dt] = __builtin_amdgcn_mfma_f32_32x32x16_bf16(vbB1, pfB1.v, o_acc[dt], 0, 0, 0);
                    }
                }
                __builtin_amdgcn_s_setprio(0);
            }
            __syncthreads();               // buf^1 staged + buf reads done
        }

        // ---- epilogue ----
        const int qrow = q0 + l31;
        if (outMode == 0) {
            const float sr = vscale / l_run;
            float* op = out + ((size_t)(b * NSEQ + qrow) * NHEAD + h) * NDIM;
            #pragma unroll
            for (int dt = 0; dt < 4; ++dt) {
                #pragma unroll
                for (int gq = 0; gq < 4; ++gq) {
                    f32x4 v = { o_acc[dt][gq * 4 + 0] * sr, o_acc[dt][gq * 4 + 1] * sr,
                                o_acc[dt][gq * 4 + 2] * sr, o_acc[dt][gq * 4 + 3] * sr };
                    *(f32x4*)(op + dt * 32 + 8 * gq + 4 * h5) = v;
                }
            }
        } else {
            const size_t hr = ((size_t)b * 1024 + (qrow - 1024)) * NHEAD + h;
            short* pp = (short*)(po + (size_t)part * NPARTH + hr * NDIM);
            #pragma unroll
            for (int dt = 0; dt < 4; ++dt) {
                #pragma unroll
                for (int gq = 0; gq < 4; ++gq) {
                    short4v v = { f2bf(o_acc[dt][gq * 4 + 0]), f2bf(o_acc[dt][gq * 4 + 1]),
                                  f2bf(o_acc[dt][gq * 4 + 2]), f2bf(o_acc[dt][gq * 4 + 3]) };
                    *(short4v*)(pp + dt * 32 + 8 * gq + 4 * h5) = v;
                }
            }
            if (h5 == 0) {
                float* mlp = ml + (size_t)part * (2 * NROWSH) + hr * 2;
                mlp[0] = m_run;
                mlp[1] = l_run;
            }
        }
    };

    if constexpr (MODE == 1) {
        const int rest = id >> 5;              // 0..7
        const int pr = rest & 3;               // supertile pair 0..3
        const int role = rest >> 2;            // 0 = A, 1 = B
        const int jH = 7 - pr, jL = pr;        // heavy/light 256-row supertiles
        const int NPH = 4 * (jH + 1);          // 64-kv phases for heavy supertile
        if (role == 0) {
            run_segment(jH * 256, 0, MIDP, 1, 0);              // heavy prefix: 18 phases
        } else {
            run_segment(jH * 256, MIDP, NPH, 1, 1);            // heavy suffix: NPH-18
            run_segment(jL * 256, 0, 4 * (jL + 1), 0, 0);      // light exact: 4(jL+1); total 18
        }
    } else {
        const int j = id >> 5;                 // supertile 0..7, exact full range
        run_segment(j * 256, 0, 4 * (j + 1), 0, 0);
    }
}

// merge heavy-row 2-way partials
__global__ __launch_bounds__(256)
void qattn_combine2(const unsigned short* __restrict__ po, const float* __restrict__ ml,
                    const float* __restrict__ qsc, const float* __restrict__ ksc,
                    const float* __restrict__ vsc, float* __restrict__ out)
{
    const int gid = blockIdx.x * 256 + threadIdx.x;   // NROWSH*16 threads
    const int hr = gid >> 4;
    const int d0 = (gid & 15) * 8;
    const int h = hr & 15;
    const int q = 1024 + ((hr >> 4) & 1023);
    const int b = hr >> 14;
    const float sc2 = qsc[h] * ksc[h] * (0.08838834764831845f * 1.4426950408889634f);
    const float m0 = ml[(size_t)hr * 2 + 0], l0 = ml[(size_t)hr * 2 + 1];
    const float m1 = ml[(size_t)2 * NROWSH + hr * 2 + 0], l1 = ml[(size_t)2 * NROWSH + hr * 2 + 1];
    const float M = fmaxf(m0, m1);
    const float w0 = exp2f((m0 - M) * sc2);
    const float w1 = exp2f((m1 - M) * sc2);
    const float sr = vsc[h] / __builtin_fmaf(w0, l0, w1 * l1);
    const float a0 = w0 * sr, a1 = w1 * sr;
    const short* x = (const short*)po + (size_t)hr * NDIM + d0;
    const short* y = (const short*)(po + NPARTH) + (size_t)hr * NDIM + d0;
    short4v x0 = *(const short4v*)x;
    short4v x1 = *(const short4v*)(x + 4);
    short4v y0 = *(const short4v*)y;
    short4v y1 = *(const short4v*)(y + 4);
    f32x4 o0, o1;
    #pragma unroll
    for (int i = 0; i < 4; ++i) {
        o0[i] = __builtin_fmaf(a0, bf2f(x0[i]), a1 * bf2f(y0[i]));
        o1[i] = __builtin_fmaf(a0, bf2f(x1[i]), a1 * bf2f(y1[i]));
    }
    float* op = out + ((size_t)(b * NSEQ + q) * NHEAD + h) * NDIM + d0;
    *(f32x4*)op = o0;
    *(f32x4*)(op + 4) = o1;
}

extern "C" void kernel_launch(void* const* d_in, const int* in_sizes, int n_in,
                              void* d_out, int out_size, void* d_ws, size_t ws_size,
                              hipStream_t stream) {
    const int* qq = (const int*)d_in[0];
    const int* kq = (const int*)d_in[1];
    const int* vq = (const int*)d_in[2];
    const float* qsc = (const float*)d_in[3];
    const float* ksc = (const float*)d_in[4];
    const float* vsc = (const float*)d_in[5];
    float* out = (float*)d_out;
    (void)in_sizes; (void)n_in; (void)out_size;

    const size_t need2 = NPARTH * 2 * sizeof(unsigned short)      // two bf16 partial halves
                       + (size_t)NROWSH * 4 * sizeof(float);      // two (m,l) arrays
    if (ws_size >= need2) {
        unsigned short* po = (unsigned short*)d_ws;
        float* ml = (float*)((char*)d_ws + NPARTH * 2 * sizeof(unsigned short));
        qattn_fwd<1><<<dim3(256), dim3(512), 0, stream>>>(qq, kq, vq, qsc, ksc, vsc, out, po, ml);
        qattn_combine2<<<dim3(NROWSH * 16 / 256), dim3(256), 0, stream>>>(po, ml, qsc, ksc, vsc, out);
    } else {
        qattn_fwd<0><<<dim3(256), dim3(512), 0, stream>>>(qq, kq, vq, qsc, ksc, vsc, out, nullptr, nullptr);
    }
}